// Round 17
// baseline (111.710 us; speedup 1.0000x reference)
//
#include <hip/hip_runtime.h>

#define CAP 32        // per-node bucket capacity (mean deg 16; overflow handled exactly)
#define OVFCAP 65536
#define NBIN_SH 6     // 64-node bins
#define BSTRIDE 1280  // records per bin (mean 1024, +8 sigma)
#define BINCHUNK 1024 // edges per bin-phase block (r16: 4096 -> 196 blocks starved the chip)

typedef __attribute__((ext_vector_type(8))) short bf16x8;
typedef __attribute__((ext_vector_type(4))) float f32x4;

__device__ __forceinline__ unsigned f2bf(float x) {
  unsigned u = __float_as_uint(x);
  return (u + 0x7fffu + ((u >> 16) & 1u)) >> 16;   // RN-even
}

__device__ __forceinline__ bf16x8 u4_to_bf(uint4 v) {
  union { uint4 u; bf16x8 b; } cv;
  cv.u = v;
  return cv.b;
}

// ---------------- zero: ovfcnt (1) + gbin (<=1023) ----------------
__global__ __launch_bounds__(1024) void zero_kernel(int* __restrict__ p, int cnt) {
  if ((int)threadIdx.x < cnt) p[threadIdx.x] = 0;
}

// ---------------- prep: bin | feat->bf16+fp8 | W->bf16, one launch ---------
// Blocks [0,nchunk): partition 1024 edges each into 64-node dst bins.
// Blocks [nchunk, nchunk+1024): cvt feat to bf16 (fb) + planar fp8 (fbq).
// Last 32 blocks: convert Ws/Wn.
__global__ __launch_bounds__(256) void prep_kernel(
    const int* __restrict__ src, const int* __restrict__ dst,
    const float* __restrict__ ew, int* __restrict__ gbin,
    uint2* __restrict__ binbuf, int* __restrict__ ovfcnt,
    uint2* __restrict__ ovf, int E,
    const float* __restrict__ feat, unsigned* __restrict__ fb,
    unsigned* __restrict__ fbq, int n,
    const float* __restrict__ Ws, const float* __restrict__ Wn,
    unsigned* __restrict__ wsb, unsigned* __restrict__ wnb,
    int nchunk, int nbins) {
  __shared__ int lcnt[1024];
  __shared__ int lbase[1024];
  const int b = blockIdx.x;
  const int tid = threadIdx.x;
  if (b < nchunk) {
    for (int i = tid; i < nbins; i += 256) lcnt[i] = 0;
    __syncthreads();
    const int e0 = b * BINCHUNK;
    const int e1 = min(E, e0 + BINCHUNK);
    int dreg[BINCHUNK / 256];          // static-indexed -> stays in VGPRs
#pragma unroll
    for (int i = 0; i < BINCHUNK / 256; ++i) {
      const int e = e0 + i * 256 + tid;
      dreg[i] = (e < e1) ? dst[e] : -1;
      if (dreg[i] >= 0) atomicAdd(&lcnt[dreg[i] >> NBIN_SH], 1);
    }
    __syncthreads();
    for (int i = tid; i < nbins; i += 256) {
      lbase[i] = lcnt[i] ? atomicAdd(&gbin[i], lcnt[i]) : 0;
      lcnt[i] = 0;
    }
    __syncthreads();
#pragma unroll
    for (int i = 0; i < BINCHUNK / 256; ++i) {
      const int e = e0 + i * 256 + tid;
      if (e < e1) {
        const int d = dreg[i];
        const int bn = d >> NBIN_SH;
        const int r = atomicAdd(&lcnt[bn], 1);
        const int pos = lbase[bn] + r;
        const uint2 rec = make_uint2(((unsigned)d << 16) | (unsigned)src[e],
                                     __float_as_uint(ew[e]));
        if (pos < BSTRIDE) {
          binbuf[(size_t)bn * BSTRIDE + pos] = rec;
        } else {                       // ~8-sigma event; exact fallback
          int p = atomicAdd(ovfcnt, 1);
          if (p < OVFCAP) ovf[p] = rec;
        }
      }
    }
  } else if (b < nchunk + 1024) {
    const int bid = b - nchunk;
    const int total4 = n * 32;
    const size_t n16 = (size_t)n * 16;
    for (int i = bid * 256 + tid; i < total4; i += 1024 * 256) {
      float4 v = ((const float4*)feat)[i];
      fb[2 * i] = f2bf(v.x) | (f2bf(v.y) << 16);
      fb[2 * i + 1] = f2bf(v.z) | (f2bf(v.w) << 16);
      unsigned q = 0;
      q = __builtin_amdgcn_cvt_pk_fp8_f32(v.x, v.y, q, false);
      q = __builtin_amdgcn_cvt_pk_fp8_f32(v.z, v.w, q, true);
      const int node = i >> 5, j = i & 31;
      // planar: plane p holds channels [64p, 64p+64) as 16 uints/node
      fbq[(size_t)(j >> 4) * n16 + (size_t)node * 16 + (j & 15)] = q;
    }
  } else {
    const int i = (b - nchunk - 1024) * 256 + tid;
    if (i < 8192) {
      float2 a = ((const float2*)Ws)[i];
      wsb[i] = f2bf(a.x) | (f2bf(a.y) << 16);
      float2 v = ((const float2*)Wn)[i];
      wnb[i] = f2bf(v.x) | (f2bf(v.y) << 16);
    }
  }
}

// ---------------- phase 2: bucket one 64-node bin in LDS, dump sequentially -
__global__ __launch_bounds__(256) void bucket_kernel(
    const int* __restrict__ gbin, const uint2* __restrict__ binbuf,
    int* __restrict__ cnt, unsigned* __restrict__ colw,
    int* __restrict__ ovfcnt, uint2* __restrict__ ovf, int n) {
  __shared__ uint4 lbucket4[64 * CAP / 4];   // 8 KB
  __shared__ int lcnt[64];
  unsigned* lbucket = (unsigned*)lbucket4;
  const int b = blockIdx.x;
  const int tid = threadIdx.x;
  if (tid < 64) lcnt[tid] = 0;
  __syncthreads();
  const int lo = b << NBIN_SH;
  const int m = min(gbin[b], BSTRIDE);
  const uint2* bb = binbuf + (size_t)b * BSTRIDE;
  for (int i = tid; i < m; i += 256) {
    const uint2 rec = bb[i];
    const int dl = (int)(rec.x >> 16) & 63;
    const int r = atomicAdd(&lcnt[dl], 1);       // counts ALL edges -> exact deg
    if (r < CAP) {
      const float w = __uint_as_float(rec.y);
      const unsigned q = (unsigned)(w * 65535.0f + 0.5f);
      lbucket[dl * CAP + r] = ((rec.x & 0xffffu) << 16) | q;
    } else {
      int p = atomicAdd(ovfcnt, 1);
      if (p < OVFCAP) ovf[p] = rec;
    }
  }
  __syncthreads();
  const int nn = min(64, n - lo);
  if (tid < nn) cnt[lo + tid] = lcnt[tid];
  const int tot4 = (nn * CAP) >> 2;
  uint4* d4 = (uint4*)(colw + (size_t)lo * CAP);
  for (int i = tid; i < tot4; i += 256) d4[i] = lbucket4[i];  // sequential 16B
}

// ---------------- gather pass (one 64-channel plane) ------------------------
// One wave per node. Lane = (g, sl): g = edge group (lane>>4), sl = channel
// slot (lane&15). 16 edges in flight per main iter; plane = 3.2MB fits
// per-XCD L2. Tail branch is wave-uniform (r15 bug: shfl from exec-masked
// lane is undefined); unwanted lanes neutralized via weight=0.
__global__ __launch_bounds__(256) void gather_kernel(
    const unsigned* __restrict__ fbqp,  // this plane's base
    const int* __restrict__ cnt,
    const unsigned* __restrict__ colw, const int* __restrict__ ovfcnt,
    const uint2* __restrict__ ovf, unsigned* __restrict__ aggu,
    int n, int plane) {
  const int wid = (blockIdx.x * 256 + threadIdx.x) >> 6;
  const int lane = threadIdx.x & 63;
  if (wid >= n) return;
  const int g = lane >> 4;
  const int sl = lane & 15;
  const int dg = cnt[wid];
  const int m = min(dg, CAP);
  const unsigned pv = (lane < m) ? colw[(size_t)wid * CAP + lane] : 0u;
  float a0 = 0.f, a1 = 0.f, a2 = 0.f, a3 = 0.f;
  const float qs = 1.0f / 65535.0f;
  int t = 0;
  for (; t + 16 <= m; t += 16) {   // 16 edges/iter: 4 per group
    unsigned p[4], u[4];
#pragma unroll
    for (int i = 0; i < 4; ++i) p[i] = __shfl(pv, t + 4 * i + g);
#pragma unroll
    for (int i = 0; i < 4; ++i) u[i] = fbqp[(size_t)(p[i] >> 16) * 16 + sl];
#pragma unroll
    for (int i = 0; i < 4; ++i) {
      const float w = (float)(p[i] & 0xffffu) * qs;
      a0 += __builtin_amdgcn_cvt_f32_fp8(u[i], 0) * w;
      a1 += __builtin_amdgcn_cvt_f32_fp8(u[i], 1) * w;
      a2 += __builtin_amdgcn_cvt_f32_fp8(u[i], 2) * w;
      a3 += __builtin_amdgcn_cvt_f32_fp8(u[i], 3) * w;
    }
  }
  for (; t + 4 <= m; t += 4) {     // 4 edges/iter: 1 per group
    const unsigned p = __shfl(pv, t + g);
    const unsigned u = fbqp[(size_t)(p >> 16) * 16 + sl];
    const float w = (float)(p & 0xffffu) * qs;
    a0 += __builtin_amdgcn_cvt_f32_fp8(u, 0) * w;
    a1 += __builtin_amdgcn_cvt_f32_fp8(u, 1) * w;
    a2 += __builtin_amdgcn_cvt_f32_fp8(u, 2) * w;
    a3 += __builtin_amdgcn_cvt_f32_fp8(u, 3) * w;
  }
  if (t < m) {                     // wave-uniform branch: ALL lanes run the shfl
    const int rem = m - t;                       // 1..3
    const int gi = (g < rem) ? g : 0;            // clamp to valid source
    const unsigned p = __shfl(pv, t + gi);       // src < m, all lanes active
    const float w = (g < rem) ? (float)(p & 0xffffu) * qs : 0.0f;
    const unsigned u = fbqp[(size_t)(p >> 16) * 16 + sl];
    a0 += __builtin_amdgcn_cvt_f32_fp8(u, 0) * w;
    a1 += __builtin_amdgcn_cvt_f32_fp8(u, 1) * w;
    a2 += __builtin_amdgcn_cvt_f32_fp8(u, 2) * w;
    a3 += __builtin_amdgcn_cvt_f32_fp8(u, 3) * w;
  }
  // inline overflow (deg>CAP nodes / bin spill); expected empty (no shfl here)
  const int novf = min(*ovfcnt, OVFCAP);
  if (novf > 0 && g == 0) {
    for (int i = 0; i < novf; ++i) {
      const uint2 v = ovf[i];
      if ((int)(v.x >> 16) == wid) {
        const unsigned u = fbqp[(size_t)(v.x & 0xffffu) * 16 + sl];
        const float w = __uint_as_float(v.y);
        a0 += __builtin_amdgcn_cvt_f32_fp8(u, 0) * w;
        a1 += __builtin_amdgcn_cvt_f32_fp8(u, 1) * w;
        a2 += __builtin_amdgcn_cvt_f32_fp8(u, 2) * w;
        a3 += __builtin_amdgcn_cvt_f32_fp8(u, 3) * w;
      }
    }
  }
  // combine 4 edge-groups: butterfly over lane bits 4,5 (all lanes active)
  a0 += __shfl_xor(a0, 16); a0 += __shfl_xor(a0, 32);
  a1 += __shfl_xor(a1, 16); a1 += __shfl_xor(a1, 32);
  a2 += __shfl_xor(a2, 16); a2 += __shfl_xor(a2, 32);
  a3 += __shfl_xor(a3, 16); a3 += __shfl_xor(a3, 32);
  if (g == 0) {
    const float sc = 1.0f / fmaxf((float)dg, 1.0f);
    const float c0 = a0 * sc, c1 = a1 * sc, c2 = a2 * sc, c3 = a3 * sc;
    uint2 o;
    o.x = f2bf(c0) | (f2bf(c1) << 16);
    o.y = f2bf(c2) | (f2bf(c3) << 16);
    // plane channels [64p+4sl, 64p+4sl+4) -> uint index 32p + 2sl
    *(uint2*)(aggu + (size_t)wid * 128 + plane * 32 + 2 * sl) = o;
  }
}

// ---------------- fused MFMA GEMM, LDS-staged W (in-place on d_out) ---------
// out[r] = feat_bf[r] @ Ws_bf.T + b + agg_bf[r] @ Wn_bf.T
__global__ __launch_bounds__(256) void fused_gemm_kernel(
    const ushort* __restrict__ fb,     // feat bf16 [n][128]
    const unsigned* __restrict__ aggu, // agg bf16 packed, row stride 128 uints
    const uint4* __restrict__ ws4,     // Ws bf16 [128][16 x 16B]
    const uint4* __restrict__ wn4,     // Wn bf16 [128][16 x 16B]
    const float* __restrict__ bsv,     // bias [128]
    float* __restrict__ out,           // final f32 (same buffer as aggu)
    int n) {
  __shared__ uint4 wlds[128 * 32];     // 64 KB
  const int tid = threadIdx.x;
  for (int i = tid; i < 2048; i += 256) {
    const int c = i >> 4, s = i & 15;
    const int sw = s ^ (c & 7);
    wlds[c * 32 + sw] = ws4[i];
    wlds[c * 32 + 16 + sw] = wn4[i];
  }
  __syncthreads();

  const int lane = tid & 63;
  const int wv = tid >> 6;
  const int row0 = (blockIdx.x * 4 + wv) * 32;
  if (row0 >= n) return;
  const int rlo = lane & 15;
  const int g = lane >> 4;

  f32x4 acc0[8], acc1[8];
#pragma unroll
  for (int ct = 0; ct < 8; ++ct) {
    const float bv = bsv[ct * 16 + rlo];
    acc0[ct] = (f32x4){bv, bv, bv, bv};
    acc1[ct] = (f32x4){bv, bv, bv, bv};
  }

  const int rA0 = min(row0 + rlo, n - 1);
  const int rA1 = min(row0 + 16 + rlo, n - 1);
  const int x7 = rlo & 7;                      // == c&7 for c = ct*16+rlo

#pragma unroll
  for (int kc = 0; kc < 4; ++kc) {
    const int k0 = kc * 32 + g * 8;
    const bf16x8 as0 = *(const bf16x8*)(fb + (size_t)rA0 * 128 + k0);
    const bf16x8 ag0 = *(const bf16x8*)(aggu + (size_t)rA0 * 128 + (k0 >> 1));
    const bf16x8 as1 = *(const bf16x8*)(fb + (size_t)rA1 * 128 + k0);
    const bf16x8 ag1 = *(const bf16x8*)(aggu + (size_t)rA1 * 128 + (k0 >> 1));
    const int slot = (kc * 4 + g) ^ x7;
#pragma unroll
    for (int ct = 0; ct < 8; ++ct) {
      const int c = ct * 16 + rlo;
      const bf16x8 bsw = u4_to_bf(wlds[c * 32 + slot]);
      const bf16x8 bnw = u4_to_bf(wlds[c * 32 + 16 + slot]);
      acc0[ct] = __builtin_amdgcn_mfma_f32_16x16x32_bf16(as0, bsw, acc0[ct], 0, 0, 0);
      acc0[ct] = __builtin_amdgcn_mfma_f32_16x16x32_bf16(ag0, bnw, acc0[ct], 0, 0, 0);
      acc1[ct] = __builtin_amdgcn_mfma_f32_16x16x32_bf16(as1, bsw, acc1[ct], 0, 0, 0);
      acc1[ct] = __builtin_amdgcn_mfma_f32_16x16x32_bf16(ag1, bnw, acc1[ct], 0, 0, 0);
    }
  }

  // C/D layout: col = ct*16 + (lane&15), row = (lane>>4)*4 + j   [m89-verified]
#pragma unroll
  for (int ct = 0; ct < 8; ++ct) {
#pragma unroll
    for (int j = 0; j < 4; ++j) {
      const int r0 = row0 + g * 4 + j;
      if (r0 < n) out[(size_t)r0 * 128 + ct * 16 + rlo] = acc0[ct][j];
      const int r1 = row0 + 16 + g * 4 + j;
      if (r1 < n) out[(size_t)r1 * 128 + ct * 16 + rlo] = acc1[ct][j];
    }
  }
}

extern "C" void kernel_launch(void* const* d_in, const int* in_sizes, int n_in,
                              void* d_out, int out_size, void* d_ws, size_t ws_size,
                              hipStream_t stream) {
  const float* feat = (const float*)d_in[0];
  const int* src = (const int*)d_in[1];
  const int* dst = (const int*)d_in[2];
  const float* ew = (const float*)d_in[3];
  const float* Wn = (const float*)d_in[4];
  const float* Ws = (const float*)d_in[5];
  const float* bs = (const float*)d_in[6];
  const int n = in_sizes[0] / 128;
  const int E = in_sizes[1];
  float* out = (float*)d_out;
  unsigned* aggu = (unsigned*)d_out;

  const int nbins = (n + 63) >> NBIN_SH;       // 64-node bins (782)

  // ws: colw 6.4 | cnt n+1+1024 | ovf 0.5 | binbuf 8 | fb 12.8 | fbq 6.4 | W
  char* w = (char*)d_ws;
  size_t off_colw = 0;
  size_t off_cnt = (off_colw + (size_t)n * CAP * 4 + 255) & ~(size_t)255;
  size_t off_ovf = (off_cnt + (size_t)(n + 1 + 1024) * 4 + 255) & ~(size_t)255;
  size_t off_binbuf = (off_ovf + (size_t)OVFCAP * 8 + 255) & ~(size_t)255;
  size_t off_fb = (off_binbuf + (size_t)nbins * BSTRIDE * 8 + 255) & ~(size_t)255;
  size_t off_fbq = (off_fb + (size_t)n * 64 * 4 + 255) & ~(size_t)255;
  size_t off_wsb = (off_fbq + (size_t)n * 32 * 4 + 255) & ~(size_t)255;
  size_t off_wnb = off_wsb + 8192 * 4;
  unsigned* colw = (unsigned*)(w + off_colw);
  int* cnt = (int*)(w + off_cnt);
  int* ovfcnt = cnt + n;
  int* gbin = cnt + n + 1;                  // nbins ints
  uint2* ovf = (uint2*)(w + off_ovf);
  uint2* binbuf = (uint2*)(w + off_binbuf);
  unsigned* fb = (unsigned*)(w + off_fb);
  unsigned* fbq = (unsigned*)(w + off_fbq);
  unsigned* wsb = (unsigned*)(w + off_wsb);
  unsigned* wnb = (unsigned*)(w + off_wnb);

  zero_kernel<<<1, 1024, 0, stream>>>(ovfcnt, 1 + nbins);

  const int nchunk = (E + BINCHUNK - 1) / BINCHUNK;
  prep_kernel<<<nchunk + 1024 + 32, 256, 0, stream>>>(
      src, dst, ew, gbin, binbuf, ovfcnt, ovf, E,
      feat, fb, fbq, n, Ws, Wn, wsb, wnb, nchunk, nbins);

  bucket_kernel<<<nbins, 256, 0, stream>>>(gbin, binbuf, cnt, colw, ovfcnt, ovf, n);

  // agg (packed bf16) -> d_out rows; two channel-plane passes (L2-resident)
  const size_t n16 = (size_t)n * 16;
  const int gblocks = (n * 64 + 255) / 256;
  gather_kernel<<<gblocks, 256, 0, stream>>>(fbq, cnt, colw, ovfcnt, ovf, aggu, n, 0);
  gather_kernel<<<gblocks, 256, 0, stream>>>(fbq + n16, cnt, colw, ovfcnt, ovf, aggu, n, 1);

  // fused: out = feat@Ws.T + b + agg@Wn.T   (in-place on d_out)
  const int nblocks = (n + 127) / 128;
  fused_gemm_kernel<<<nblocks, 256, 0, stream>>>(
      (const ushort*)fb, aggu, (const uint4*)wsb, (const uint4*)wnb, bs, out, n);
}

// Round 18
// 87.199 us; speedup vs baseline: 1.2811x; 1.2811x over previous
//
#include <hip/hip_runtime.h>

#define CAP 32        // per-node bucket capacity (mean deg 16; overflow handled exactly)
#define OVFCAP 65536
#define NBIN_SH 8     // 256-node bins (r14-proven geometry)
#define BSTRIDE 5120  // records per bin (mean 4096, +16 sigma)
#define BINCHUNK 4096 // edges per bin-phase block (196 blocks; ~21-record runs/bin)

typedef __attribute__((ext_vector_type(8))) short bf16x8;
typedef __attribute__((ext_vector_type(4))) float f32x4;

__device__ __forceinline__ unsigned f2bf(float x) {
  unsigned u = __float_as_uint(x);
  return (u + 0x7fffu + ((u >> 16) & 1u)) >> 16;   // RN-even
}

__device__ __forceinline__ bf16x8 u4_to_bf(uint4 v) {
  union { uint4 u; bf16x8 b; } cv;
  cv.u = v;
  return cv.b;
}

// ---------------- zero: ovfcnt (1) + gbin (256) ----------------
__global__ __launch_bounds__(512) void zero_kernel(int* __restrict__ p) {
  if (threadIdx.x < 257) p[threadIdx.x] = 0;
}

// ---------------- prep: bin | feat->bf16+fp8(planar) | W->bf16 -------------
// Blocks [0,nchunk): partition 4096 edges each into 256-node dst bins.
// Blocks [nchunk, nchunk+1024): cvt feat to bf16 (fb) + planar fp8 (fbq).
// Last 32 blocks: convert Ws/Wn.  (r14 geometry; r17's 1024-edge chunks
// fragmented binbuf runs to ~1.3 records -> scattered-write amplification.)
__global__ __launch_bounds__(256) void prep_kernel(
    const int* __restrict__ src, const int* __restrict__ dst,
    const float* __restrict__ ew, int* __restrict__ gbin,
    uint2* __restrict__ binbuf, int* __restrict__ ovfcnt,
    uint2* __restrict__ ovf, int E,
    const float* __restrict__ feat, unsigned* __restrict__ fb,
    unsigned* __restrict__ fbq, int n,
    const float* __restrict__ Ws, const float* __restrict__ Wn,
    unsigned* __restrict__ wsb, unsigned* __restrict__ wnb,
    int nchunk) {
  __shared__ int lcnt[256];
  __shared__ int lbase[256];
  const int b = blockIdx.x;
  const int tid = threadIdx.x;
  if (b < nchunk) {
    lcnt[tid] = 0;
    __syncthreads();
    const int e0 = b * BINCHUNK;
    const int e1 = min(E, e0 + BINCHUNK);
    int dreg[BINCHUNK / 256];          // static-indexed -> stays in VGPRs
#pragma unroll
    for (int i = 0; i < BINCHUNK / 256; ++i) {
      const int e = e0 + i * 256 + tid;
      dreg[i] = (e < e1) ? dst[e] : -1;
      if (dreg[i] >= 0) atomicAdd(&lcnt[dreg[i] >> NBIN_SH], 1);
    }
    __syncthreads();
    lbase[tid] = lcnt[tid] ? atomicAdd(&gbin[tid], lcnt[tid]) : 0;
    lcnt[tid] = 0;
    __syncthreads();
#pragma unroll
    for (int i = 0; i < BINCHUNK / 256; ++i) {
      const int e = e0 + i * 256 + tid;
      if (e < e1) {
        const int d = dreg[i];
        const int bn = d >> NBIN_SH;
        const int r = atomicAdd(&lcnt[bn], 1);
        const int pos = lbase[bn] + r;
        const uint2 rec = make_uint2(((unsigned)d << 16) | (unsigned)src[e],
                                     __float_as_uint(ew[e]));
        if (pos < BSTRIDE) {
          binbuf[(size_t)bn * BSTRIDE + pos] = rec;
        } else {                       // ~16-sigma event; exact fallback
          int p = atomicAdd(ovfcnt, 1);
          if (p < OVFCAP) ovf[p] = rec;
        }
      }
    }
  } else if (b < nchunk + 1024) {
    const int bid = b - nchunk;
    const int total4 = n * 32;
    const size_t n16 = (size_t)n * 16;
    for (int i = bid * 256 + tid; i < total4; i += 1024 * 256) {
      float4 v = ((const float4*)feat)[i];
      fb[2 * i] = f2bf(v.x) | (f2bf(v.y) << 16);
      fb[2 * i + 1] = f2bf(v.z) | (f2bf(v.w) << 16);
      unsigned q = 0;
      q = __builtin_amdgcn_cvt_pk_fp8_f32(v.x, v.y, q, false);
      q = __builtin_amdgcn_cvt_pk_fp8_f32(v.z, v.w, q, true);
      const int node = i >> 5, j = i & 31;
      // planar: plane p holds channels [64p, 64p+64) as 16 uints/node
      fbq[(size_t)(j >> 4) * n16 + (size_t)node * 16 + (j & 15)] = q;
    }
  } else {
    const int i = (b - nchunk - 1024) * 256 + tid;
    if (i < 8192) {
      float2 a = ((const float2*)Ws)[i];
      wsb[i] = f2bf(a.x) | (f2bf(a.y) << 16);
      float2 v = ((const float2*)Wn)[i];
      wnb[i] = f2bf(v.x) | (f2bf(v.y) << 16);
    }
  }
}

// ---------------- phase 2: bucket one 256-node bin in LDS (512 thr) --------
__global__ __launch_bounds__(512) void bucket_kernel(
    const int* __restrict__ gbin, const uint2* __restrict__ binbuf,
    int* __restrict__ cnt, unsigned* __restrict__ colw,
    int* __restrict__ ovfcnt, uint2* __restrict__ ovf, int n) {
  __shared__ uint4 lbucket4[256 * CAP / 4];   // 32 KB
  __shared__ int lcnt[256];
  unsigned* lbucket = (unsigned*)lbucket4;
  const int b = blockIdx.x;
  const int tid = threadIdx.x;
  if (tid < 256) lcnt[tid] = 0;
  __syncthreads();
  const int lo = b << NBIN_SH;
  const int m = min(gbin[b], BSTRIDE);
  const uint2* bb = binbuf + (size_t)b * BSTRIDE;
  for (int i = tid; i < m; i += 512) {
    const uint2 rec = bb[i];
    const int dl = (int)(rec.x >> 16) & 255;
    const int r = atomicAdd(&lcnt[dl], 1);       // counts ALL edges -> exact deg
    if (r < CAP) {
      const float w = __uint_as_float(rec.y);
      const unsigned q = (unsigned)(w * 65535.0f + 0.5f);
      lbucket[dl * CAP + r] = ((rec.x & 0xffffu) << 16) | q;
    } else {
      int p = atomicAdd(ovfcnt, 1);
      if (p < OVFCAP) ovf[p] = rec;
    }
  }
  __syncthreads();
  const int nn = min(256, n - lo);
  if (tid < nn) cnt[lo + tid] = lcnt[tid];
  const int tot4 = (nn * CAP) >> 2;
  uint4* d4 = (uint4*)(colw + (size_t)lo * CAP);
  for (int i = tid; i < tot4; i += 512) d4[i] = lbucket4[i];  // sequential 16B
}

// ---------------- gather pass (one 64-channel plane) ------------------------
// One wave per node. Lane = (g, sl): g = edge group (lane>>4), sl = channel
// slot (lane&15). 16 edges in flight per main iter; plane = 3.2MB fits
// per-XCD L2. Tail branch is wave-uniform (r15 bug: shfl from exec-masked
// lane is undefined); unwanted lanes neutralized via weight=0.
__global__ __launch_bounds__(256) void gather_kernel(
    const unsigned* __restrict__ fbqp,  // this plane's base
    const int* __restrict__ cnt,
    const unsigned* __restrict__ colw, const int* __restrict__ ovfcnt,
    const uint2* __restrict__ ovf, unsigned* __restrict__ aggu,
    int n, int plane) {
  const int wid = (blockIdx.x * 256 + threadIdx.x) >> 6;
  const int lane = threadIdx.x & 63;
  if (wid >= n) return;
  const int g = lane >> 4;
  const int sl = lane & 15;
  const int dg = cnt[wid];
  const int m = min(dg, CAP);
  const unsigned pv = (lane < m) ? colw[(size_t)wid * CAP + lane] : 0u;
  float a0 = 0.f, a1 = 0.f, a2 = 0.f, a3 = 0.f;
  const float qs = 1.0f / 65535.0f;
  int t = 0;
  for (; t + 16 <= m; t += 16) {   // 16 edges/iter: 4 per group
    unsigned p[4], u[4];
#pragma unroll
    for (int i = 0; i < 4; ++i) p[i] = __shfl(pv, t + 4 * i + g);
#pragma unroll
    for (int i = 0; i < 4; ++i) u[i] = fbqp[(size_t)(p[i] >> 16) * 16 + sl];
#pragma unroll
    for (int i = 0; i < 4; ++i) {
      const float w = (float)(p[i] & 0xffffu) * qs;
      a0 += __builtin_amdgcn_cvt_f32_fp8(u[i], 0) * w;
      a1 += __builtin_amdgcn_cvt_f32_fp8(u[i], 1) * w;
      a2 += __builtin_amdgcn_cvt_f32_fp8(u[i], 2) * w;
      a3 += __builtin_amdgcn_cvt_f32_fp8(u[i], 3) * w;
    }
  }
  for (; t + 4 <= m; t += 4) {     // 4 edges/iter: 1 per group
    const unsigned p = __shfl(pv, t + g);
    const unsigned u = fbqp[(size_t)(p >> 16) * 16 + sl];
    const float w = (float)(p & 0xffffu) * qs;
    a0 += __builtin_amdgcn_cvt_f32_fp8(u, 0) * w;
    a1 += __builtin_amdgcn_cvt_f32_fp8(u, 1) * w;
    a2 += __builtin_amdgcn_cvt_f32_fp8(u, 2) * w;
    a3 += __builtin_amdgcn_cvt_f32_fp8(u, 3) * w;
  }
  if (t < m) {                     // wave-uniform branch: ALL lanes run the shfl
    const int rem = m - t;                       // 1..3
    const int gi = (g < rem) ? g : 0;            // clamp to valid source
    const unsigned p = __shfl(pv, t + gi);       // src < m, all lanes active
    const float w = (g < rem) ? (float)(p & 0xffffu) * qs : 0.0f;
    const unsigned u = fbqp[(size_t)(p >> 16) * 16 + sl];
    a0 += __builtin_amdgcn_cvt_f32_fp8(u, 0) * w;
    a1 += __builtin_amdgcn_cvt_f32_fp8(u, 1) * w;
    a2 += __builtin_amdgcn_cvt_f32_fp8(u, 2) * w;
    a3 += __builtin_amdgcn_cvt_f32_fp8(u, 3) * w;
  }
  // inline overflow (deg>CAP nodes / bin spill); expected empty (no shfl here)
  const int novf = min(*ovfcnt, OVFCAP);
  if (novf > 0 && g == 0) {
    for (int i = 0; i < novf; ++i) {
      const uint2 v = ovf[i];
      if ((int)(v.x >> 16) == wid) {
        const unsigned u = fbqp[(size_t)(v.x & 0xffffu) * 16 + sl];
        const float w = __uint_as_float(v.y);
        a0 += __builtin_amdgcn_cvt_f32_fp8(u, 0) * w;
        a1 += __builtin_amdgcn_cvt_f32_fp8(u, 1) * w;
        a2 += __builtin_amdgcn_cvt_f32_fp8(u, 2) * w;
        a3 += __builtin_amdgcn_cvt_f32_fp8(u, 3) * w;
      }
    }
  }
  // combine 4 edge-groups: butterfly over lane bits 4,5 (all lanes active)
  a0 += __shfl_xor(a0, 16); a0 += __shfl_xor(a0, 32);
  a1 += __shfl_xor(a1, 16); a1 += __shfl_xor(a1, 32);
  a2 += __shfl_xor(a2, 16); a2 += __shfl_xor(a2, 32);
  a3 += __shfl_xor(a3, 16); a3 += __shfl_xor(a3, 32);
  if (g == 0) {
    const float sc = 1.0f / fmaxf((float)dg, 1.0f);
    const float c0 = a0 * sc, c1 = a1 * sc, c2 = a2 * sc, c3 = a3 * sc;
    uint2 o;
    o.x = f2bf(c0) | (f2bf(c1) << 16);
    o.y = f2bf(c2) | (f2bf(c3) << 16);
    // plane channels [64p+4sl, 64p+4sl+4) -> uint index 32p + 2sl
    *(uint2*)(aggu + (size_t)wid * 128 + plane * 32 + 2 * sl) = o;
  }
}

// ---------------- fused MFMA GEMM, LDS-staged W (in-place on d_out) ---------
// out[r] = feat_bf[r] @ Ws_bf.T + b + agg_bf[r] @ Wn_bf.T
__global__ __launch_bounds__(256) void fused_gemm_kernel(
    const ushort* __restrict__ fb,     // feat bf16 [n][128]
    const unsigned* __restrict__ aggu, // agg bf16 packed, row stride 128 uints
    const uint4* __restrict__ ws4,     // Ws bf16 [128][16 x 16B]
    const uint4* __restrict__ wn4,     // Wn bf16 [128][16 x 16B]
    const float* __restrict__ bsv,     // bias [128]
    float* __restrict__ out,           // final f32 (same buffer as aggu)
    int n) {
  __shared__ uint4 wlds[128 * 32];     // 64 KB
  const int tid = threadIdx.x;
  for (int i = tid; i < 2048; i += 256) {
    const int c = i >> 4, s = i & 15;
    const int sw = s ^ (c & 7);
    wlds[c * 32 + sw] = ws4[i];
    wlds[c * 32 + 16 + sw] = wn4[i];
  }
  __syncthreads();

  const int lane = tid & 63;
  const int wv = tid >> 6;
  const int row0 = (blockIdx.x * 4 + wv) * 32;
  if (row0 >= n) return;
  const int rlo = lane & 15;
  const int g = lane >> 4;

  f32x4 acc0[8], acc1[8];
#pragma unroll
  for (int ct = 0; ct < 8; ++ct) {
    const float bv = bsv[ct * 16 + rlo];
    acc0[ct] = (f32x4){bv, bv, bv, bv};
    acc1[ct] = (f32x4){bv, bv, bv, bv};
  }

  const int rA0 = min(row0 + rlo, n - 1);
  const int rA1 = min(row0 + 16 + rlo, n - 1);
  const int x7 = rlo & 7;                      // == c&7 for c = ct*16+rlo

#pragma unroll
  for (int kc = 0; kc < 4; ++kc) {
    const int k0 = kc * 32 + g * 8;
    const bf16x8 as0 = *(const bf16x8*)(fb + (size_t)rA0 * 128 + k0);
    const bf16x8 ag0 = *(const bf16x8*)(aggu + (size_t)rA0 * 128 + (k0 >> 1));
    const bf16x8 as1 = *(const bf16x8*)(fb + (size_t)rA1 * 128 + k0);
    const bf16x8 ag1 = *(const bf16x8*)(aggu + (size_t)rA1 * 128 + (k0 >> 1));
    const int slot = (kc * 4 + g) ^ x7;
#pragma unroll
    for (int ct = 0; ct < 8; ++ct) {
      const int c = ct * 16 + rlo;
      const bf16x8 bsw = u4_to_bf(wlds[c * 32 + slot]);
      const bf16x8 bnw = u4_to_bf(wlds[c * 32 + 16 + slot]);
      acc0[ct] = __builtin_amdgcn_mfma_f32_16x16x32_bf16(as0, bsw, acc0[ct], 0, 0, 0);
      acc0[ct] = __builtin_amdgcn_mfma_f32_16x16x32_bf16(ag0, bnw, acc0[ct], 0, 0, 0);
      acc1[ct] = __builtin_amdgcn_mfma_f32_16x16x32_bf16(as1, bsw, acc1[ct], 0, 0, 0);
      acc1[ct] = __builtin_amdgcn_mfma_f32_16x16x32_bf16(ag1, bnw, acc1[ct], 0, 0, 0);
    }
  }

  // C/D layout: col = ct*16 + (lane&15), row = (lane>>4)*4 + j   [m89-verified]
#pragma unroll
  for (int ct = 0; ct < 8; ++ct) {
#pragma unroll
    for (int j = 0; j < 4; ++j) {
      const int r0 = row0 + g * 4 + j;
      if (r0 < n) out[(size_t)r0 * 128 + ct * 16 + rlo] = acc0[ct][j];
      const int r1 = row0 + 16 + g * 4 + j;
      if (r1 < n) out[(size_t)r1 * 128 + ct * 16 + rlo] = acc1[ct][j];
    }
  }
}

extern "C" void kernel_launch(void* const* d_in, const int* in_sizes, int n_in,
                              void* d_out, int out_size, void* d_ws, size_t ws_size,
                              hipStream_t stream) {
  const float* feat = (const float*)d_in[0];
  const int* src = (const int*)d_in[1];
  const int* dst = (const int*)d_in[2];
  const float* ew = (const float*)d_in[3];
  const float* Wn = (const float*)d_in[4];
  const float* Ws = (const float*)d_in[5];
  const float* bs = (const float*)d_in[6];
  const int n = in_sizes[0] / 128;
  const int E = in_sizes[1];
  float* out = (float*)d_out;
  unsigned* aggu = (unsigned*)d_out;

  const int nbins = (n + 255) >> NBIN_SH;      // 256-node bins (196)

  // ws: colw 6.4 | cnt n+1+256 | ovf 0.5 | binbuf 8 | fb 12.8 | fbq 6.4 | W
  char* w = (char*)d_ws;
  size_t off_colw = 0;
  size_t off_cnt = (off_colw + (size_t)n * CAP * 4 + 255) & ~(size_t)255;
  size_t off_ovf = (off_cnt + (size_t)(n + 1 + 256) * 4 + 255) & ~(size_t)255;
  size_t off_binbuf = (off_ovf + (size_t)OVFCAP * 8 + 255) & ~(size_t)255;
  size_t off_fb = (off_binbuf + (size_t)nbins * BSTRIDE * 8 + 255) & ~(size_t)255;
  size_t off_fbq = (off_fb + (size_t)n * 64 * 4 + 255) & ~(size_t)255;
  size_t off_wsb = (off_fbq + (size_t)n * 32 * 4 + 255) & ~(size_t)255;
  size_t off_wnb = off_wsb + 8192 * 4;
  unsigned* colw = (unsigned*)(w + off_colw);
  int* cnt = (int*)(w + off_cnt);
  int* ovfcnt = cnt + n;
  int* gbin = cnt + n + 1;                  // 256 ints
  uint2* ovf = (uint2*)(w + off_ovf);
  uint2* binbuf = (uint2*)(w + off_binbuf);
  unsigned* fb = (unsigned*)(w + off_fb);
  unsigned* fbq = (unsigned*)(w + off_fbq);
  unsigned* wsb = (unsigned*)(w + off_wsb);
  unsigned* wnb = (unsigned*)(w + off_wnb);

  zero_kernel<<<1, 512, 0, stream>>>(ovfcnt);   // ovfcnt + gbin (257 ints)

  const int nchunk = (E + BINCHUNK - 1) / BINCHUNK;
  prep_kernel<<<nchunk + 1024 + 32, 256, 0, stream>>>(
      src, dst, ew, gbin, binbuf, ovfcnt, ovf, E,
      feat, fb, fbq, n, Ws, Wn, wsb, wnb, nchunk);

  bucket_kernel<<<nbins, 512, 0, stream>>>(gbin, binbuf, cnt, colw, ovfcnt, ovf, n);

  // agg (packed bf16) -> d_out rows; two channel-plane passes (L2-resident)
  const size_t n16 = (size_t)n * 16;
  const int gblocks = (n * 64 + 255) / 256;
  gather_kernel<<<gblocks, 256, 0, stream>>>(fbq, cnt, colw, ovfcnt, ovf, aggu, n, 0);
  gather_kernel<<<gblocks, 256, 0, stream>>>(fbq + n16, cnt, colw, ovfcnt, ovf, aggu, n, 1);

  // fused: out = feat@Ws.T + b + agg@Wn.T   (in-place on d_out)
  const int nblocks = (n + 127) / 128;
  fused_gemm_kernel<<<nblocks, 256, 0, stream>>>(
      (const ushort*)fb, aggu, (const uint4*)wsb, (const uint4*)wnb, bs, out, n);
}

// Round 19
// 72.252 us; speedup vs baseline: 1.5461x; 1.2069x over previous
//
#include <hip/hip_runtime.h>

#define CAP 32        // per-node bucket capacity (mean deg 16; overflow handled exactly)
#define OVFCAP 65536
#define NBIN_SH 8     // 256-node bins (r14-proven geometry)
#define BSTRIDE 5120  // records per bin (mean 4096, +16 sigma)
#define BINCHUNK 4096 // edges per bin-phase block (196 blocks; ~21-record runs/bin)

typedef __attribute__((ext_vector_type(8))) short bf16x8;
typedef __attribute__((ext_vector_type(4))) float f32x4;

__device__ __forceinline__ unsigned f2bf(float x) {
  unsigned u = __float_as_uint(x);
  return (u + 0x7fffu + ((u >> 16) & 1u)) >> 16;   // RN-even
}

__device__ __forceinline__ bf16x8 u4_to_bf(uint4 v) {
  union { uint4 u; bf16x8 b; } cv;
  cv.u = v;
  return cv.b;
}

// ---------------- zero: ovfcnt (1) + gbin (256) ----------------
__global__ __launch_bounds__(512) void zero_kernel(int* __restrict__ p) {
  if (threadIdx.x < 257) p[threadIdx.x] = 0;
}

// ---------------- prep: bin | feat->bf16+fp8 | W->bf16, one launch ---------
// Blocks [0,nchunk): partition 4096 edges each into 256-node dst bins.
// Blocks [nchunk, nchunk+1024): cvt feat to bf16 (fb) + interleaved fp8 (fbq).
// Last 32 blocks: convert Ws/Wn.
__global__ __launch_bounds__(256) void prep_kernel(
    const int* __restrict__ src, const int* __restrict__ dst,
    const float* __restrict__ ew, int* __restrict__ gbin,
    uint2* __restrict__ binbuf, int* __restrict__ ovfcnt,
    uint2* __restrict__ ovf, int E,
    const float* __restrict__ feat, unsigned* __restrict__ fb,
    unsigned* __restrict__ fbq, int n,
    const float* __restrict__ Ws, const float* __restrict__ Wn,
    unsigned* __restrict__ wsb, unsigned* __restrict__ wnb,
    int nchunk) {
  __shared__ int lcnt[256];
  __shared__ int lbase[256];
  const int b = blockIdx.x;
  const int tid = threadIdx.x;
  if (b < nchunk) {
    lcnt[tid] = 0;
    __syncthreads();
    const int e0 = b * BINCHUNK;
    const int e1 = min(E, e0 + BINCHUNK);
    int dreg[BINCHUNK / 256];          // static-indexed -> stays in VGPRs
#pragma unroll
    for (int i = 0; i < BINCHUNK / 256; ++i) {
      const int e = e0 + i * 256 + tid;
      dreg[i] = (e < e1) ? dst[e] : -1;
      if (dreg[i] >= 0) atomicAdd(&lcnt[dreg[i] >> NBIN_SH], 1);
    }
    __syncthreads();
    lbase[tid] = lcnt[tid] ? atomicAdd(&gbin[tid], lcnt[tid]) : 0;
    lcnt[tid] = 0;
    __syncthreads();
#pragma unroll
    for (int i = 0; i < BINCHUNK / 256; ++i) {
      const int e = e0 + i * 256 + tid;
      if (e < e1) {
        const int d = dreg[i];
        const int bn = d >> NBIN_SH;
        const int r = atomicAdd(&lcnt[bn], 1);
        const int pos = lbase[bn] + r;
        const uint2 rec = make_uint2(((unsigned)d << 16) | (unsigned)src[e],
                                     __float_as_uint(ew[e]));
        if (pos < BSTRIDE) {
          binbuf[(size_t)bn * BSTRIDE + pos] = rec;
        } else {                       // ~16-sigma event; exact fallback
          int p = atomicAdd(ovfcnt, 1);
          if (p < OVFCAP) ovf[p] = rec;
        }
      }
    }
  } else if (b < nchunk + 1024) {
    const int bid = b - nchunk;
    const int total4 = n * 32;
    for (int i = bid * 256 + tid; i < total4; i += 1024 * 256) {
      float4 v = ((const float4*)feat)[i];
      fb[2 * i] = f2bf(v.x) | (f2bf(v.y) << 16);
      fb[2 * i + 1] = f2bf(v.z) | (f2bf(v.w) << 16);
      unsigned q = 0;
      q = __builtin_amdgcn_cvt_pk_fp8_f32(v.x, v.y, q, false);
      q = __builtin_amdgcn_cvt_pk_fp8_f32(v.z, v.w, q, true);
      fbq[i] = q;                      // interleaved [n][32] uints
    }
  } else {
    const int i = (b - nchunk - 1024) * 256 + tid;
    if (i < 8192) {
      float2 a = ((const float2*)Ws)[i];
      wsb[i] = f2bf(a.x) | (f2bf(a.y) << 16);
      float2 v = ((const float2*)Wn)[i];
      wnb[i] = f2bf(v.x) | (f2bf(v.y) << 16);
    }
  }
}

// ---------------- phase 2: bucket one 256-node bin in LDS (512 thr) --------
__global__ __launch_bounds__(512) void bucket_kernel(
    const int* __restrict__ gbin, const uint2* __restrict__ binbuf,
    int* __restrict__ cnt, unsigned* __restrict__ colw,
    int* __restrict__ ovfcnt, uint2* __restrict__ ovf, int n) {
  __shared__ uint4 lbucket4[256 * CAP / 4];   // 32 KB
  __shared__ int lcnt[256];
  unsigned* lbucket = (unsigned*)lbucket4;
  const int b = blockIdx.x;
  const int tid = threadIdx.x;
  if (tid < 256) lcnt[tid] = 0;
  __syncthreads();
  const int lo = b << NBIN_SH;
  const int m = min(gbin[b], BSTRIDE);
  const uint2* bb = binbuf + (size_t)b * BSTRIDE;
  for (int i = tid; i < m; i += 512) {
    const uint2 rec = bb[i];
    const int dl = (int)(rec.x >> 16) & 255;
    const int r = atomicAdd(&lcnt[dl], 1);       // counts ALL edges -> exact deg
    if (r < CAP) {
      const float w = __uint_as_float(rec.y);
      const unsigned q = (unsigned)(w * 65535.0f + 0.5f);
      lbucket[dl * CAP + r] = ((rec.x & 0xffffu) << 16) | q;
    } else {
      int p = atomicAdd(ovfcnt, 1);
      if (p < OVFCAP) ovf[p] = rec;
    }
  }
  __syncthreads();
  const int nn = min(256, n - lo);
  if (tid < nn) cnt[lo + tid] = lcnt[tid];
  const int tot4 = (nn * CAP) >> 2;
  uint4* d4 = (uint4*)(colw + (size_t)lo * CAP);
  for (int i = tid; i < tot4; i += 512) d4[i] = lbucket4[i];  // sequential 16B
}

// ---------------- gather (fp8, single pass, r14 form) + inline overflow -----
// One wave per dst node. Lane = (g, sl): g = edge-parity group (lane>>5),
// sl = channel slot (lane&31) owning channels [4sl,4sl+4) via one uint.
// 16-wide main loop: 8 independent fbq loads per group in flight.
// Odd-edge tail is SAFE here: source lane t < m <= CAP=32 is always within
// active group 0 (lanes 0-31) — unlike r15's 4-group variant (ERRATA).
__global__ __launch_bounds__(256) void gather_kernel(
    const unsigned* __restrict__ fbq, const int* __restrict__ cnt,
    const unsigned* __restrict__ colw, const int* __restrict__ ovfcnt,
    const uint2* __restrict__ ovf, unsigned* __restrict__ aggu, int n) {
  const int wid = (blockIdx.x * 256 + threadIdx.x) >> 6;
  const int lane = threadIdx.x & 63;
  if (wid >= n) return;
  const int g = lane >> 5;
  const int sl = lane & 31;
  const int dg = cnt[wid];
  const int m = min(dg, CAP);
  const unsigned pv = (lane < m) ? colw[(size_t)wid * CAP + lane] : 0u;
  float a0 = 0.f, a1 = 0.f, a2 = 0.f, a3 = 0.f;
  const float qs = 1.0f / 65535.0f;
  int t = 0;
  for (; t + 16 <= m; t += 16) {   // 16 edges/iter: 8 per group
    unsigned p[8], u[8];
#pragma unroll
    for (int i = 0; i < 8; ++i) p[i] = __shfl(pv, t + 2 * i + g);
#pragma unroll
    for (int i = 0; i < 8; ++i) u[i] = fbq[(size_t)(p[i] >> 16) * 32 + sl];
#pragma unroll
    for (int i = 0; i < 8; ++i) {
      const float w = (float)(p[i] & 0xffffu) * qs;
      a0 += __builtin_amdgcn_cvt_f32_fp8(u[i], 0) * w;
      a1 += __builtin_amdgcn_cvt_f32_fp8(u[i], 1) * w;
      a2 += __builtin_amdgcn_cvt_f32_fp8(u[i], 2) * w;
      a3 += __builtin_amdgcn_cvt_f32_fp8(u[i], 3) * w;
    }
  }
  if (t + 8 <= m) {                // 8 edges: 4 per group
    unsigned p[4], u[4];
#pragma unroll
    for (int i = 0; i < 4; ++i) p[i] = __shfl(pv, t + 2 * i + g);
#pragma unroll
    for (int i = 0; i < 4; ++i) u[i] = fbq[(size_t)(p[i] >> 16) * 32 + sl];
#pragma unroll
    for (int i = 0; i < 4; ++i) {
      const float w = (float)(p[i] & 0xffffu) * qs;
      a0 += __builtin_amdgcn_cvt_f32_fp8(u[i], 0) * w;
      a1 += __builtin_amdgcn_cvt_f32_fp8(u[i], 1) * w;
      a2 += __builtin_amdgcn_cvt_f32_fp8(u[i], 2) * w;
      a3 += __builtin_amdgcn_cvt_f32_fp8(u[i], 3) * w;
    }
    t += 8;
  }
  for (; t + 2 <= m; t += 2) {     // 2 edges/iter
    const unsigned p = __shfl(pv, t + g);
    const unsigned u = fbq[(size_t)(p >> 16) * 32 + sl];
    const float w = (float)(p & 0xffffu) * qs;
    a0 += __builtin_amdgcn_cvt_f32_fp8(u, 0) * w;
    a1 += __builtin_amdgcn_cvt_f32_fp8(u, 1) * w;
    a2 += __builtin_amdgcn_cvt_f32_fp8(u, 2) * w;
    a3 += __builtin_amdgcn_cvt_f32_fp8(u, 3) * w;
  }
  if (t < m && g == 0) {           // odd tail: source lane t < 32 = active
    const unsigned p = __shfl(pv, t);
    const unsigned u = fbq[(size_t)(p >> 16) * 32 + sl];
    const float w = (float)(p & 0xffffu) * qs;
    a0 += __builtin_amdgcn_cvt_f32_fp8(u, 0) * w;
    a1 += __builtin_amdgcn_cvt_f32_fp8(u, 1) * w;
    a2 += __builtin_amdgcn_cvt_f32_fp8(u, 2) * w;
    a3 += __builtin_amdgcn_cvt_f32_fp8(u, 3) * w;
  }
  // inline overflow (deg>CAP nodes / bin spill); expected empty
  const int novf = min(*ovfcnt, OVFCAP);
  if (novf > 0 && g == 0) {
    for (int i = 0; i < novf; ++i) {
      const uint2 v = ovf[i];
      if ((int)(v.x >> 16) == wid) {
        const unsigned u = fbq[(size_t)(v.x & 0xffffu) * 32 + sl];
        const float w = __uint_as_float(v.y);
        a0 += __builtin_amdgcn_cvt_f32_fp8(u, 0) * w;
        a1 += __builtin_amdgcn_cvt_f32_fp8(u, 1) * w;
        a2 += __builtin_amdgcn_cvt_f32_fp8(u, 2) * w;
        a3 += __builtin_amdgcn_cvt_f32_fp8(u, 3) * w;
      }
    }
  }
  // combine the two edge-groups: lane<32 adds lane+32's accumulators
  const int peer = (lane + 32) & 63;
  const float b0 = __shfl(a0, peer);
  const float b1 = __shfl(a1, peer);
  const float b2 = __shfl(a2, peer);
  const float b3 = __shfl(a3, peer);
  if (g == 0) {
    const float sc = 1.0f / fmaxf((float)dg, 1.0f);
    const float c0 = (a0 + b0) * sc, c1 = (a1 + b1) * sc;
    const float c2 = (a2 + b2) * sc, c3 = (a3 + b3) * sc;
    uint2 o;
    o.x = f2bf(c0) | (f2bf(c1) << 16);
    o.y = f2bf(c2) | (f2bf(c3) << 16);
    *(uint2*)(aggu + (size_t)wid * 128 + 2 * sl) = o;
  }
}

// ---------------- fused MFMA GEMM, LDS-staged W (in-place on d_out) ---------
// out[r] = feat_bf[r] @ Ws_bf.T + b + agg_bf[r] @ Wn_bf.T
__global__ __launch_bounds__(256) void fused_gemm_kernel(
    const ushort* __restrict__ fb,     // feat bf16 [n][128]
    const unsigned* __restrict__ aggu, // agg bf16 packed, row stride 128 uints
    const uint4* __restrict__ ws4,     // Ws bf16 [128][16 x 16B]
    const uint4* __restrict__ wn4,     // Wn bf16 [128][16 x 16B]
    const float* __restrict__ bsv,     // bias [128]
    float* __restrict__ out,           // final f32 (same buffer as aggu)
    int n) {
  __shared__ uint4 wlds[128 * 32];     // 64 KB
  const int tid = threadIdx.x;
  for (int i = tid; i < 2048; i += 256) {
    const int c = i >> 4, s = i & 15;
    const int sw = s ^ (c & 7);
    wlds[c * 32 + sw] = ws4[i];
    wlds[c * 32 + 16 + sw] = wn4[i];
  }
  __syncthreads();

  const int lane = tid & 63;
  const int wv = tid >> 6;
  const int row0 = (blockIdx.x * 4 + wv) * 32;
  if (row0 >= n) return;
  const int rlo = lane & 15;
  const int g = lane >> 4;

  f32x4 acc0[8], acc1[8];
#pragma unroll
  for (int ct = 0; ct < 8; ++ct) {
    const float bv = bsv[ct * 16 + rlo];
    acc0[ct] = (f32x4){bv, bv, bv, bv};
    acc1[ct] = (f32x4){bv, bv, bv, bv};
  }

  const int rA0 = min(row0 + rlo, n - 1);
  const int rA1 = min(row0 + 16 + rlo, n - 1);
  const int x7 = rlo & 7;                      // == c&7 for c = ct*16+rlo

#pragma unroll
  for (int kc = 0; kc < 4; ++kc) {
    const int k0 = kc * 32 + g * 8;
    const bf16x8 as0 = *(const bf16x8*)(fb + (size_t)rA0 * 128 + k0);
    const bf16x8 ag0 = *(const bf16x8*)(aggu + (size_t)rA0 * 128 + (k0 >> 1));
    const bf16x8 as1 = *(const bf16x8*)(fb + (size_t)rA1 * 128 + k0);
    const bf16x8 ag1 = *(const bf16x8*)(aggu + (size_t)rA1 * 128 + (k0 >> 1));
    const int slot = (kc * 4 + g) ^ x7;
#pragma unroll
    for (int ct = 0; ct < 8; ++ct) {
      const int c = ct * 16 + rlo;
      const bf16x8 bsw = u4_to_bf(wlds[c * 32 + slot]);
      const bf16x8 bnw = u4_to_bf(wlds[c * 32 + 16 + slot]);
      acc0[ct] = __builtin_amdgcn_mfma_f32_16x16x32_bf16(as0, bsw, acc0[ct], 0, 0, 0);
      acc0[ct] = __builtin_amdgcn_mfma_f32_16x16x32_bf16(ag0, bnw, acc0[ct], 0, 0, 0);
      acc1[ct] = __builtin_amdgcn_mfma_f32_16x16x32_bf16(as1, bsw, acc1[ct], 0, 0, 0);
      acc1[ct] = __builtin_amdgcn_mfma_f32_16x16x32_bf16(ag1, bnw, acc1[ct], 0, 0, 0);
    }
  }

  // C/D layout: col = ct*16 + (lane&15), row = (lane>>4)*4 + j   [m89-verified]
#pragma unroll
  for (int ct = 0; ct < 8; ++ct) {
#pragma unroll
    for (int j = 0; j < 4; ++j) {
      const int r0 = row0 + g * 4 + j;
      if (r0 < n) out[(size_t)r0 * 128 + ct * 16 + rlo] = acc0[ct][j];
      const int r1 = row0 + 16 + g * 4 + j;
      if (r1 < n) out[(size_t)r1 * 128 + ct * 16 + rlo] = acc1[ct][j];
    }
  }
}

extern "C" void kernel_launch(void* const* d_in, const int* in_sizes, int n_in,
                              void* d_out, int out_size, void* d_ws, size_t ws_size,
                              hipStream_t stream) {
  const float* feat = (const float*)d_in[0];
  const int* src = (const int*)d_in[1];
  const int* dst = (const int*)d_in[2];
  const float* ew = (const float*)d_in[3];
  const float* Wn = (const float*)d_in[4];
  const float* Ws = (const float*)d_in[5];
  const float* bs = (const float*)d_in[6];
  const int n = in_sizes[0] / 128;
  const int E = in_sizes[1];
  float* out = (float*)d_out;
  unsigned* aggu = (unsigned*)d_out;

  const int nbins = (n + 255) >> NBIN_SH;      // 256-node bins (196)

  // ws: colw 6.4 | cnt n+1+256 | ovf 0.5 | binbuf 8 | fb 12.8 | fbq 6.4 | W
  char* w = (char*)d_ws;
  size_t off_colw = 0;
  size_t off_cnt = (off_colw + (size_t)n * CAP * 4 + 255) & ~(size_t)255;
  size_t off_ovf = (off_cnt + (size_t)(n + 1 + 256) * 4 + 255) & ~(size_t)255;
  size_t off_binbuf = (off_ovf + (size_t)OVFCAP * 8 + 255) & ~(size_t)255;
  size_t off_fb = (off_binbuf + (size_t)nbins * BSTRIDE * 8 + 255) & ~(size_t)255;
  size_t off_fbq = (off_fb + (size_t)n * 64 * 4 + 255) & ~(size_t)255;
  size_t off_wsb = (off_fbq + (size_t)n * 32 * 4 + 255) & ~(size_t)255;
  size_t off_wnb = off_wsb + 8192 * 4;
  unsigned* colw = (unsigned*)(w + off_colw);
  int* cnt = (int*)(w + off_cnt);
  int* ovfcnt = cnt + n;
  int* gbin = cnt + n + 1;                  // 256 ints
  uint2* ovf = (uint2*)(w + off_ovf);
  uint2* binbuf = (uint2*)(w + off_binbuf);
  unsigned* fb = (unsigned*)(w + off_fb);
  unsigned* fbq = (unsigned*)(w + off_fbq);
  unsigned* wsb = (unsigned*)(w + off_wsb);
  unsigned* wnb = (unsigned*)(w + off_wnb);

  zero_kernel<<<1, 512, 0, stream>>>(ovfcnt);   // ovfcnt + gbin (257 ints)

  const int nchunk = (E + BINCHUNK - 1) / BINCHUNK;
  prep_kernel<<<nchunk + 1024 + 32, 256, 0, stream>>>(
      src, dst, ew, gbin, binbuf, ovfcnt, ovf, E,
      feat, fb, fbq, n, Ws, Wn, wsb, wnb, nchunk);

  bucket_kernel<<<nbins, 512, 0, stream>>>(gbin, binbuf, cnt, colw, ovfcnt, ovf, n);

  // agg (packed bf16) -> d_out rows; single pass, interleaved fbq (r14 form)
  gather_kernel<<<(n * 64 + 255) / 256, 256, 0, stream>>>(
      fbq, cnt, colw, ovfcnt, ovf, aggu, n);

  // fused: out = feat@Ws.T + b + agg@Wn.T   (in-place on d_out)
  const int nblocks = (n + 127) / 128;
  fused_gemm_kernel<<<nblocks, 256, 0, stream>>>(
      (const ushort*)fb, aggu, (const uint4*)wsb, (const uint4*)wnb, bs, out, n);
}

// Round 20
// 71.111 us; speedup vs baseline: 1.5709x; 1.0160x over previous
//
#include <hip/hip_runtime.h>

#define CAP 32        // per-node bucket capacity (mean deg 16; overflow handled exactly)
#define OVFCAP 65536
#define NBIN_SH 8     // 256-node bins (r14/r19-proven geometry)
#define BSTRIDE 5120  // records per bin (mean 4096, +16 sigma)
#define BINCHUNK 8192 // edges per bin-phase block (512 thr; ~42-record runs/bin)
#define BINTHREADS 512

typedef __attribute__((ext_vector_type(8))) short bf16x8;
typedef __attribute__((ext_vector_type(4))) float f32x4;

__device__ __forceinline__ unsigned f2bf(float x) {
  unsigned u = __float_as_uint(x);
  return (u + 0x7fffu + ((u >> 16) & 1u)) >> 16;   // RN-even
}

__device__ __forceinline__ bf16x8 u4_to_bf(uint4 v) {
  union { uint4 u; bf16x8 b; } cv;
  cv.u = v;
  return cv.b;
}

// ---------------- zero: ovfcnt (1) + gbin (256) ----------------
__global__ __launch_bounds__(512) void zero_kernel(int* __restrict__ p) {
  if (threadIdx.x < 257) p[threadIdx.x] = 0;
}

// ---------------- prep_bin: partition edges into 256-node dst bins ---------
// 512 threads, 8192 edges/block: 98 blocks x 8 waves (same 784-wave
// parallelism as r19's 196x4) but ~42-record binbuf runs (336B) -> fewer
// partial-line write boundaries (r17 showed short runs amplify writes).
__global__ __launch_bounds__(BINTHREADS) void prep_kernel(
    const int* __restrict__ src, const int* __restrict__ dst,
    const float* __restrict__ ew, int* __restrict__ gbin,
    uint2* __restrict__ binbuf, int* __restrict__ ovfcnt,
    uint2* __restrict__ ovf, int E,
    const float* __restrict__ feat, unsigned* __restrict__ fb,
    unsigned* __restrict__ fbq, int n,
    const float* __restrict__ Ws, const float* __restrict__ Wn,
    unsigned* __restrict__ wsb, unsigned* __restrict__ wnb,
    int nchunk) {
  __shared__ int lcnt[256];
  __shared__ int lbase[256];
  const int b = blockIdx.x;
  const int tid = threadIdx.x;
  if (b < nchunk) {
    if (tid < 256) lcnt[tid] = 0;
    __syncthreads();
    const int e0 = b * BINCHUNK;
    const int e1 = min(E, e0 + BINCHUNK);
    int dreg[BINCHUNK / BINTHREADS];   // static-indexed -> stays in VGPRs
#pragma unroll
    for (int i = 0; i < BINCHUNK / BINTHREADS; ++i) {
      const int e = e0 + i * BINTHREADS + tid;
      dreg[i] = (e < e1) ? dst[e] : -1;
      if (dreg[i] >= 0) atomicAdd(&lcnt[dreg[i] >> NBIN_SH], 1);
    }
    __syncthreads();
    if (tid < 256) {
      lbase[tid] = lcnt[tid] ? atomicAdd(&gbin[tid], lcnt[tid]) : 0;
      lcnt[tid] = 0;
    }
    __syncthreads();
#pragma unroll
    for (int i = 0; i < BINCHUNK / BINTHREADS; ++i) {
      const int e = e0 + i * BINTHREADS + tid;
      if (e < e1) {
        const int d = dreg[i];
        const int bn = d >> NBIN_SH;
        const int r = atomicAdd(&lcnt[bn], 1);
        const int pos = lbase[bn] + r;
        const uint2 rec = make_uint2(((unsigned)d << 16) | (unsigned)src[e],
                                     __float_as_uint(ew[e]));
        if (pos < BSTRIDE) {
          binbuf[(size_t)bn * BSTRIDE + pos] = rec;
        } else {                       // ~16-sigma event; exact fallback
          int p = atomicAdd(ovfcnt, 1);
          if (p < OVFCAP) ovf[p] = rec;
        }
      }
    }
  } else if (b < nchunk + 1024) {
    const int bid = b - nchunk;
    const int total4 = n * 32;
    for (int i = bid * BINTHREADS + tid; i < total4; i += 1024 * BINTHREADS) {
      float4 v = ((const float4*)feat)[i];
      fb[2 * i] = f2bf(v.x) | (f2bf(v.y) << 16);
      fb[2 * i + 1] = f2bf(v.z) | (f2bf(v.w) << 16);
      unsigned q = 0;
      q = __builtin_amdgcn_cvt_pk_fp8_f32(v.x, v.y, q, false);
      q = __builtin_amdgcn_cvt_pk_fp8_f32(v.z, v.w, q, true);
      fbq[i] = q;                      // interleaved [n][32] uints
    }
  } else {
    const int i = (b - nchunk - 1024) * BINTHREADS + tid;
    if (i < 8192) {
      float2 a = ((const float2*)Ws)[i];
      wsb[i] = f2bf(a.x) | (f2bf(a.y) << 16);
      float2 v = ((const float2*)Wn)[i];
      wnb[i] = f2bf(v.x) | (f2bf(v.y) << 16);
    }
  }
}

// ---------------- phase 2: bucket one 256-node bin in LDS (512 thr) --------
__global__ __launch_bounds__(512) void bucket_kernel(
    const int* __restrict__ gbin, const uint2* __restrict__ binbuf,
    int* __restrict__ cnt, unsigned* __restrict__ colw,
    int* __restrict__ ovfcnt, uint2* __restrict__ ovf, int n) {
  __shared__ uint4 lbucket4[256 * CAP / 4];   // 32 KB
  __shared__ int lcnt[256];
  unsigned* lbucket = (unsigned*)lbucket4;
  const int b = blockIdx.x;
  const int tid = threadIdx.x;
  if (tid < 256) lcnt[tid] = 0;
  __syncthreads();
  const int lo = b << NBIN_SH;
  const int m = min(gbin[b], BSTRIDE);
  const uint2* bb = binbuf + (size_t)b * BSTRIDE;
  for (int i = tid; i < m; i += 512) {
    const uint2 rec = bb[i];
    const int dl = (int)(rec.x >> 16) & 255;
    const int r = atomicAdd(&lcnt[dl], 1);       // counts ALL edges -> exact deg
    if (r < CAP) {
      const float w = __uint_as_float(rec.y);
      const unsigned q = (unsigned)(w * 65535.0f + 0.5f);
      lbucket[dl * CAP + r] = ((rec.x & 0xffffu) << 16) | q;
    } else {
      int p = atomicAdd(ovfcnt, 1);
      if (p < OVFCAP) ovf[p] = rec;
    }
  }
  __syncthreads();
  const int nn = min(256, n - lo);
  if (tid < nn) cnt[lo + tid] = lcnt[tid];
  const int tot4 = (nn * CAP) >> 2;
  uint4* d4 = (uint4*)(colw + (size_t)lo * CAP);
  for (int i = tid; i < tot4; i += 512) d4[i] = lbucket4[i];  // sequential 16B
}

// ---------------- gather (fp8, single pass) + inline overflow ---------------
// One wave per dst node. Lane = (g, sl): g = edge-parity group (lane>>5),
// sl = channel slot (lane&31) owning channels [4sl,4sl+4) via one uint.
// 16-wide main loop: 8 independent fbq loads per group in flight.
// Odd-edge tail SAFE: source lane t < m <= CAP=32 is within active group 0.
__global__ __launch_bounds__(256) void gather_kernel(
    const unsigned* __restrict__ fbq, const int* __restrict__ cnt,
    const unsigned* __restrict__ colw, const int* __restrict__ ovfcnt,
    const uint2* __restrict__ ovf, unsigned* __restrict__ aggu, int n) {
  const int wid = (blockIdx.x * 256 + threadIdx.x) >> 6;
  const int lane = threadIdx.x & 63;
  if (wid >= n) return;
  const int g = lane >> 5;
  const int sl = lane & 31;
  const int dg = cnt[wid];
  const int m = min(dg, CAP);
  const unsigned pv = (lane < m) ? colw[(size_t)wid * CAP + lane] : 0u;
  float a0 = 0.f, a1 = 0.f, a2 = 0.f, a3 = 0.f;
  const float qs = 1.0f / 65535.0f;
  int t = 0;
  for (; t + 16 <= m; t += 16) {   // 16 edges/iter: 8 per group
    unsigned p[8], u[8];
#pragma unroll
    for (int i = 0; i < 8; ++i) p[i] = __shfl(pv, t + 2 * i + g);
#pragma unroll
    for (int i = 0; i < 8; ++i) u[i] = fbq[(size_t)(p[i] >> 16) * 32 + sl];
#pragma unroll
    for (int i = 0; i < 8; ++i) {
      const float w = (float)(p[i] & 0xffffu) * qs;
      a0 += __builtin_amdgcn_cvt_f32_fp8(u[i], 0) * w;
      a1 += __builtin_amdgcn_cvt_f32_fp8(u[i], 1) * w;
      a2 += __builtin_amdgcn_cvt_f32_fp8(u[i], 2) * w;
      a3 += __builtin_amdgcn_cvt_f32_fp8(u[i], 3) * w;
    }
  }
  if (t + 8 <= m) {                // 8 edges: 4 per group
    unsigned p[4], u[4];
#pragma unroll
    for (int i = 0; i < 4; ++i) p[i] = __shfl(pv, t + 2 * i + g);
#pragma unroll
    for (int i = 0; i < 4; ++i) u[i] = fbq[(size_t)(p[i] >> 16) * 32 + sl];
#pragma unroll
    for (int i = 0; i < 4; ++i) {
      const float w = (float)(p[i] & 0xffffu) * qs;
      a0 += __builtin_amdgcn_cvt_f32_fp8(u[i], 0) * w;
      a1 += __builtin_amdgcn_cvt_f32_fp8(u[i], 1) * w;
      a2 += __builtin_amdgcn_cvt_f32_fp8(u[i], 2) * w;
      a3 += __builtin_amdgcn_cvt_f32_fp8(u[i], 3) * w;
    }
    t += 8;
  }
  for (; t + 2 <= m; t += 2) {     // 2 edges/iter
    const unsigned p = __shfl(pv, t + g);
    const unsigned u = fbq[(size_t)(p >> 16) * 32 + sl];
    const float w = (float)(p & 0xffffu) * qs;
    a0 += __builtin_amdgcn_cvt_f32_fp8(u, 0) * w;
    a1 += __builtin_amdgcn_cvt_f32_fp8(u, 1) * w;
    a2 += __builtin_amdgcn_cvt_f32_fp8(u, 2) * w;
    a3 += __builtin_amdgcn_cvt_f32_fp8(u, 3) * w;
  }
  if (t < m && g == 0) {           // odd tail: source lane t < 32 = active
    const unsigned p = __shfl(pv, t);
    const unsigned u = fbq[(size_t)(p >> 16) * 32 + sl];
    const float w = (float)(p & 0xffffu) * qs;
    a0 += __builtin_amdgcn_cvt_f32_fp8(u, 0) * w;
    a1 += __builtin_amdgcn_cvt_f32_fp8(u, 1) * w;
    a2 += __builtin_amdgcn_cvt_f32_fp8(u, 2) * w;
    a3 += __builtin_amdgcn_cvt_f32_fp8(u, 3) * w;
  }
  // inline overflow (deg>CAP nodes / bin spill); expected empty
  const int novf = min(*ovfcnt, OVFCAP);
  if (novf > 0 && g == 0) {
    for (int i = 0; i < novf; ++i) {
      const uint2 v = ovf[i];
      if ((int)(v.x >> 16) == wid) {
        const unsigned u = fbq[(size_t)(v.x & 0xffffu) * 32 + sl];
        const float w = __uint_as_float(v.y);
        a0 += __builtin_amdgcn_cvt_f32_fp8(u, 0) * w;
        a1 += __builtin_amdgcn_cvt_f32_fp8(u, 1) * w;
        a2 += __builtin_amdgcn_cvt_f32_fp8(u, 2) * w;
        a3 += __builtin_amdgcn_cvt_f32_fp8(u, 3) * w;
      }
    }
  }
  // combine the two edge-groups: lane<32 adds lane+32's accumulators
  const int peer = (lane + 32) & 63;
  const float b0 = __shfl(a0, peer);
  const float b1 = __shfl(a1, peer);
  const float b2 = __shfl(a2, peer);
  const float b3 = __shfl(a3, peer);
  if (g == 0) {
    const float sc = 1.0f / fmaxf((float)dg, 1.0f);
    const float c0 = (a0 + b0) * sc, c1 = (a1 + b1) * sc;
    const float c2 = (a2 + b2) * sc, c3 = (a3 + b3) * sc;
    uint2 o;
    o.x = f2bf(c0) | (f2bf(c1) << 16);
    o.y = f2bf(c2) | (f2bf(c3) << 16);
    *(uint2*)(aggu + (size_t)wid * 128 + 2 * sl) = o;
  }
}

// ---------------- fused MFMA GEMM, LDS-staged W (in-place on d_out) ---------
// out[r] = feat_bf[r] @ Ws_bf.T + b + agg_bf[r] @ Wn_bf.T
__global__ __launch_bounds__(256) void fused_gemm_kernel(
    const ushort* __restrict__ fb,     // feat bf16 [n][128]
    const unsigned* __restrict__ aggu, // agg bf16 packed, row stride 128 uints
    const uint4* __restrict__ ws4,     // Ws bf16 [128][16 x 16B]
    const uint4* __restrict__ wn4,     // Wn bf16 [128][16 x 16B]
    const float* __restrict__ bsv,     // bias [128]
    float* __restrict__ out,           // final f32 (same buffer as aggu)
    int n) {
  __shared__ uint4 wlds[128 * 32];     // 64 KB
  const int tid = threadIdx.x;
  for (int i = tid; i < 2048; i += 256) {
    const int c = i >> 4, s = i & 15;
    const int sw = s ^ (c & 7);
    wlds[c * 32 + sw] = ws4[i];
    wlds[c * 32 + 16 + sw] = wn4[i];
  }
  __syncthreads();

  const int lane = tid & 63;
  const int wv = tid >> 6;
  const int row0 = (blockIdx.x * 4 + wv) * 32;
  if (row0 >= n) return;
  const int rlo = lane & 15;
  const int g = lane >> 4;

  f32x4 acc0[8], acc1[8];
#pragma unroll
  for (int ct = 0; ct < 8; ++ct) {
    const float bv = bsv[ct * 16 + rlo];
    acc0[ct] = (f32x4){bv, bv, bv, bv};
    acc1[ct] = (f32x4){bv, bv, bv, bv};
  }

  const int rA0 = min(row0 + rlo, n - 1);
  const int rA1 = min(row0 + 16 + rlo, n - 1);
  const int x7 = rlo & 7;                      // == c&7 for c = ct*16+rlo

#pragma unroll
  for (int kc = 0; kc < 4; ++kc) {
    const int k0 = kc * 32 + g * 8;
    const bf16x8 as0 = *(const bf16x8*)(fb + (size_t)rA0 * 128 + k0);
    const bf16x8 ag0 = *(const bf16x8*)(aggu + (size_t)rA0 * 128 + (k0 >> 1));
    const bf16x8 as1 = *(const bf16x8*)(fb + (size_t)rA1 * 128 + k0);
    const bf16x8 ag1 = *(const bf16x8*)(aggu + (size_t)rA1 * 128 + (k0 >> 1));
    const int slot = (kc * 4 + g) ^ x7;
#pragma unroll
    for (int ct = 0; ct < 8; ++ct) {
      const int c = ct * 16 + rlo;
      const bf16x8 bsw = u4_to_bf(wlds[c * 32 + slot]);
      const bf16x8 bnw = u4_to_bf(wlds[c * 32 + 16 + slot]);
      acc0[ct] = __builtin_amdgcn_mfma_f32_16x16x32_bf16(as0, bsw, acc0[ct], 0, 0, 0);
      acc0[ct] = __builtin_amdgcn_mfma_f32_16x16x32_bf16(ag0, bnw, acc0[ct], 0, 0, 0);
      acc1[ct] = __builtin_amdgcn_mfma_f32_16x16x32_bf16(as1, bsw, acc1[ct], 0, 0, 0);
      acc1[ct] = __builtin_amdgcn_mfma_f32_16x16x32_bf16(ag1, bnw, acc1[ct], 0, 0, 0);
    }
  }

  // C/D layout: col = ct*16 + (lane&15), row = (lane>>4)*4 + j   [m89-verified]
#pragma unroll
  for (int ct = 0; ct < 8; ++ct) {
#pragma unroll
    for (int j = 0; j < 4; ++j) {
      const int r0 = row0 + g * 4 + j;
      if (r0 < n) out[(size_t)r0 * 128 + ct * 16 + rlo] = acc0[ct][j];
      const int r1 = row0 + 16 + g * 4 + j;
      if (r1 < n) out[(size_t)r1 * 128 + ct * 16 + rlo] = acc1[ct][j];
    }
  }
}

extern "C" void kernel_launch(void* const* d_in, const int* in_sizes, int n_in,
                              void* d_out, int out_size, void* d_ws, size_t ws_size,
                              hipStream_t stream) {
  const float* feat = (const float*)d_in[0];
  const int* src = (const int*)d_in[1];
  const int* dst = (const int*)d_in[2];
  const float* ew = (const float*)d_in[3];
  const float* Wn = (const float*)d_in[4];
  const float* Ws = (const float*)d_in[5];
  const float* bs = (const float*)d_in[6];
  const int n = in_sizes[0] / 128;
  const int E = in_sizes[1];
  float* out = (float*)d_out;
  unsigned* aggu = (unsigned*)d_out;

  const int nbins = (n + 255) >> NBIN_SH;      // 256-node bins (196)

  // ws: colw 6.4 | cnt n+1+256 | ovf 0.5 | binbuf 8 | fb 12.8 | fbq 6.4 | W
  char* w = (char*)d_ws;
  size_t off_colw = 0;
  size_t off_cnt = (off_colw + (size_t)n * CAP * 4 + 255) & ~(size_t)255;
  size_t off_ovf = (off_cnt + (size_t)(n + 1 + 256) * 4 + 255) & ~(size_t)255;
  size_t off_binbuf = (off_ovf + (size_t)OVFCAP * 8 + 255) & ~(size_t)255;
  size_t off_fb = (off_binbuf + (size_t)nbins * BSTRIDE * 8 + 255) & ~(size_t)255;
  size_t off_fbq = (off_fb + (size_t)n * 64 * 4 + 255) & ~(size_t)255;
  size_t off_wsb = (off_fbq + (size_t)n * 32 * 4 + 255) & ~(size_t)255;
  size_t off_wnb = off_wsb + 8192 * 4;
  unsigned* colw = (unsigned*)(w + off_colw);
  int* cnt = (int*)(w + off_cnt);
  int* ovfcnt = cnt + n;
  int* gbin = cnt + n + 1;                  // 256 ints
  uint2* ovf = (uint2*)(w + off_ovf);
  uint2* binbuf = (uint2*)(w + off_binbuf);
  unsigned* fb = (unsigned*)(w + off_fb);
  unsigned* fbq = (unsigned*)(w + off_fbq);
  unsigned* wsb = (unsigned*)(w + off_wsb);
  unsigned* wnb = (unsigned*)(w + off_wnb);

  zero_kernel<<<1, 512, 0, stream>>>(ovfcnt);   // ovfcnt + gbin (257 ints)

  const int nchunk = (E + BINCHUNK - 1) / BINCHUNK;
  prep_kernel<<<nchunk + 1024 + 32, BINTHREADS, 0, stream>>>(
      src, dst, ew, gbin, binbuf, ovfcnt, ovf, E,
      feat, fb, fbq, n, Ws, Wn, wsb, wnb, nchunk);

  bucket_kernel<<<nbins, 512, 0, stream>>>(gbin, binbuf, cnt, colw, ovfcnt, ovf, n);

  // agg (packed bf16) -> d_out rows; single pass, interleaved fbq
  gather_kernel<<<(n * 64 + 255) / 256, 256, 0, stream>>>(
      fbq, cnt, colw, ovfcnt, ovf, aggu, n);

  // fused: out = feat@Ws.T + b + agg@Wn.T   (in-place on d_out)
  const int nblocks = (n + 127) / 128;
  fused_gemm_kernel<<<nblocks, 256, 0, stream>>>(
      (const ushort*)fb, aggu, (const uint4*)wsb, (const uint4*)wnb, bs, out, n);
}